// Round 1
// baseline (614.133 us; speedup 1.0000x reference)
//
#include <hip/hip_runtime.h>
#include <math.h>

// Problem constants (from reference): [SQ, B, NP, HN] fp32
#define SQ 2048
#define BATCH 2
#define NPH 16
#define HN 64
#define BQ 64            // query rows per block
#define BK 64            // key rows per tile
#define SSTRIDE (BATCH*NPH*HN)   // 2048 floats between consecutive s
#define LDP 68           // padded LDS leading dim (68*4B = 272B, 16B-aligned rows)

// One block = one (b,n) head x 64-row Q tile. 256 threads = 16x16 thread grid,
// each thread owns a 4x4 register sub-tile of the 64x64 score/output tiles.
__global__ __launch_bounds__(256, 2)
void fattn_fp32(const float* __restrict__ Q, const float* __restrict__ K,
                const float* __restrict__ V, float* __restrict__ O) {
  __shared__ float qt[HN][LDP];   // qt[h][r]  (Q tile, transposed)
  __shared__ float kt[HN][LDP];   // kt[h][c]  (K tile, transposed)
  __shared__ float vt[BK][LDP];   // vt[c][h]  (V tile, natural)
  __shared__ float pt[BK][LDP];   // pt[c][r]  (P tile, transposed)

  const int t  = threadIdx.x;
  const int ty = t >> 4;          // 0..15 -> rows ty*4..ty*4+3
  const int tx = t & 15;          // 0..15 -> cols tx*4..tx*4+3
  const int q0 = blockIdx.x * BQ; // query-tile base row
  const int bn = blockIdx.y;      // b*NPH + n
  const size_t head_off = (size_t)bn * HN;

  // ---- stage Q tile (transposed) ----
  {
    const int r  = t >> 2;        // 0..63
    const int fq = t & 3;
    const float* qrow = Q + (size_t)(q0 + r) * SSTRIDE + head_off;
    #pragma unroll
    for (int i = 0; i < 4; ++i) {
      const int f4 = fq + i * 4;  // 0..15
      float4 v4 = *(const float4*)(qrow + f4 * 4);
      qt[f4*4+0][r] = v4.x;
      qt[f4*4+1][r] = v4.y;
      qt[f4*4+2][r] = v4.z;
      qt[f4*4+3][r] = v4.w;
    }
  }

  float m_i[4], l_i[4], acc[4][4];
  #pragma unroll
  for (int i = 0; i < 4; ++i) {
    m_i[i] = -INFINITY; l_i[i] = 0.f;
    #pragma unroll
    for (int j = 0; j < 4; ++j) acc[i][j] = 0.f;
  }

  for (int kt0 = 0; kt0 < SQ; kt0 += BK) {
    __syncthreads();  // previous iteration's PV readers done before restaging
    // ---- stage K (transposed) and V (natural) ----
    {
      const int c  = t >> 2;      // 0..63
      const int fq = t & 3;
      const float* krow = K + (size_t)(kt0 + c) * SSTRIDE + head_off;
      const float* vrow = V + (size_t)(kt0 + c) * SSTRIDE + head_off;
      #pragma unroll
      for (int i = 0; i < 4; ++i) {
        const int f4 = fq + i * 4;
        float4 kv4 = *(const float4*)(krow + f4 * 4);
        kt[f4*4+0][c] = kv4.x;
        kt[f4*4+1][c] = kv4.y;
        kt[f4*4+2][c] = kv4.z;
        kt[f4*4+3][c] = kv4.w;
        float4 vv4 = *(const float4*)(vrow + f4 * 4);
        *(float4*)&vt[c][f4*4] = vv4;
      }
    }
    __syncthreads();

    // ---- scores: S[64][64] = Qtile . Ktile^T, 4x4 per thread ----
    float s[4][4];
    #pragma unroll
    for (int i = 0; i < 4; ++i)
      #pragma unroll
      for (int j = 0; j < 4; ++j) s[i][j] = 0.f;

    #pragma unroll 4
    for (int h = 0; h < HN; ++h) {
      const float4 qv = *(const float4*)&qt[h][ty*4];
      const float4 kv = *(const float4*)&kt[h][tx*4];
      const float qa[4] = {qv.x, qv.y, qv.z, qv.w};
      const float ka[4] = {kv.x, kv.y, kv.z, kv.w};
      #pragma unroll
      for (int i = 0; i < 4; ++i)
        #pragma unroll
        for (int j = 0; j < 4; ++j)
          s[i][j] = fmaf(qa[i], ka[j], s[i][j]);
    }

    // ---- online softmax (row stats replicated across the 16 tx lanes) ----
    #pragma unroll
    for (int i = 0; i < 4; ++i) {
      float mx = fmaxf(fmaxf(s[i][0], s[i][1]), fmaxf(s[i][2], s[i][3]));
      #pragma unroll
      for (int off = 1; off < 16; off <<= 1)
        mx = fmaxf(mx, __shfl_xor(mx, off, 64));
      const float mnew  = fmaxf(m_i[i], mx);
      const float alpha = __expf(m_i[i] - mnew);   // 0 on first tile (m=-inf)
      m_i[i] = mnew;
      float rsum = 0.f;
      #pragma unroll
      for (int j = 0; j < 4; ++j) {
        const float p = __expf(s[i][j] - mnew);
        s[i][j] = p;
        rsum += p;
      }
      #pragma unroll
      for (int off = 1; off < 16; off <<= 1)
        rsum += __shfl_xor(rsum, off, 64);
      l_i[i] = l_i[i] * alpha + rsum;
      #pragma unroll
      for (int j = 0; j < 4; ++j) acc[i][j] *= alpha;
    }

    // ---- write P transposed to LDS: pt[c][r] = P[r][c] ----
    #pragma unroll
    for (int j = 0; j < 4; ++j) {
      float4 pv;
      pv.x = s[0][j]; pv.y = s[1][j]; pv.z = s[2][j]; pv.w = s[3][j];
      *(float4*)&pt[tx*4 + j][ty*4] = pv;
    }
    __syncthreads();

    // ---- PV: acc[r][h] += sum_c P[r][c] * V[c][h] ----
    #pragma unroll 4
    for (int c = 0; c < BK; ++c) {
      const float4 pv = *(const float4*)&pt[c][ty*4];
      const float4 vv = *(const float4*)&vt[c][tx*4];
      const float pa[4] = {pv.x, pv.y, pv.z, pv.w};
      const float va[4] = {vv.x, vv.y, vv.z, vv.w};
      #pragma unroll
      for (int i = 0; i < 4; ++i)
        #pragma unroll
        for (int j = 0; j < 4; ++j)
          acc[i][j] = fmaf(pa[i], va[j], acc[i][j]);
    }
  }

  // ---- epilogue: normalize by l and store ----
  #pragma unroll
  for (int i = 0; i < 4; ++i) {
    const float inv = 1.f / l_i[i];
    const int r = q0 + ty * 4 + i;
    float4 o;
    o.x = acc[i][0] * inv;
    o.y = acc[i][1] * inv;
    o.z = acc[i][2] * inv;
    o.w = acc[i][3] * inv;
    *(float4*)(O + (size_t)r * SSTRIDE + head_off + tx * 4) = o;
  }
}

extern "C" void kernel_launch(void* const* d_in, const int* in_sizes, int n_in,
                              void* d_out, int out_size, void* d_ws, size_t ws_size,
                              hipStream_t stream) {
  const float* Q = (const float*)d_in[0];
  const float* K = (const float*)d_in[1];
  const float* V = (const float*)d_in[2];
  float* O = (float*)d_out;
  dim3 grid(SQ / BQ, BATCH * NPH);   // 32 x 32 = 1024 blocks
  dim3 block(256);
  fattn_fp32<<<grid, block, 0, stream>>>(Q, K, V, O);
}

// Round 3
// 152.992 us; speedup vs baseline: 4.0141x; 4.0141x over previous
//
#include <hip/hip_runtime.h>
#include <math.h>

// [SQ, B, NP, HN] fp32, unscaled QK^T softmax attention.
#define SQ 2048
#define NBH 32           // B*NP heads
#define HN 64
#define BQ 128           // queries per block (4 waves x 32)
#define BK 64            // keys per tile
#define TOK 2048         // floats between consecutive tokens (B*NP*HN)
#define LDK 72           // padded LDS leading dim (144 B, 16B-divisible)

typedef _Float16 half2v __attribute__((ext_vector_type(2)));
typedef _Float16 half4v __attribute__((ext_vector_type(4)));
typedef _Float16 half8v __attribute__((ext_vector_type(8)));
typedef float f32x16 __attribute__((ext_vector_type(16)));

// One block = one head x 128-query tile. Wave w owns queries q0+w*32 .. +31.
// S^T = K.Q^T via mfma_32x32x16_f16 (A=K from LDS, B=Q in regs).
// 32x32 C layout (verified m74/m101): col = lane&31, row = (reg&3)+8*(reg>>2)+4*(lane>>5)
// => per-query softmax state is per-lane uniform; one shfl_xor(32) completes reductions.
// PV uses a PERMUTED k-order pi(h,j) = 16ks + 4h + 8*(j>>2) + (j&3) so the P^T
// B-operand is exactly the C-layout registers (packed pairwise) -- no LDS roundtrip.
__global__ __launch_bounds__(256, 3)
void fattn_mfma(const float* __restrict__ Q, const float* __restrict__ K,
                const float* __restrict__ V, float* __restrict__ O) {
  __shared__ __align__(16) _Float16 kb[BK][LDK];  // [key][dim] f16
  __shared__ __align__(16) _Float16 vt[HN][LDK];  // [dim][key] f16, 8-key blocks xor-swizzled by (dim>>3)&7

  const int t = threadIdx.x;
  const int lane = t & 63;
  const int w = t >> 6;
  const int h2 = lane >> 5;        // half-wave
  const int l31 = lane & 31;
  const int q0 = blockIdx.x * BQ + w * 32;
  const size_t hoff = (size_t)blockIdx.y * HN;

  // ---- Q B-fragments, kept in registers all kernel ----
  // B layout: n = query = lane&31, k = dim = 8*h2 + j (+16*ks)
  half8v qf[4];
  {
    const float* qp = Q + (size_t)(q0 + l31) * TOK + hoff + 8 * h2;
    #pragma unroll
    for (int ks = 0; ks < 4; ++ks) {
      float4 a = *(const float4*)(qp + 16 * ks);
      float4 b = *(const float4*)(qp + 16 * ks + 4);
      half8v f;
      f[0] = (_Float16)a.x; f[1] = (_Float16)a.y; f[2] = (_Float16)a.z; f[3] = (_Float16)a.w;
      f[4] = (_Float16)b.x; f[5] = (_Float16)b.y; f[6] = (_Float16)b.z; f[7] = (_Float16)b.w;
      qf[ks] = f;
    }
  }

  f32x16 acc0, acc1;   // O^T frags: dim blocks 0..31, 32..63
  #pragma unroll
  for (int r = 0; r < 16; ++r) { acc0[r] = 0.f; acc1[r] = 0.f; }
  float m_i = -INFINITY, l_i = 0.f;

  for (int kt = 0; kt < SQ; kt += BK) {
    __syncthreads();
    // ---- stage K [key][dim] as f16 ----
    {
      const int key = t >> 2, qq = t & 3;
      const float* kp = K + (size_t)(kt + key) * TOK + hoff;
      #pragma unroll
      for (int i = 0; i < 4; ++i) {
        const int d = qq * 4 + i * 16;   // 64B-contiguous per 4 threads
        float4 x = *(const float4*)(kp + d);
        half4v h;
        h[0] = (_Float16)x.x; h[1] = (_Float16)x.y; h[2] = (_Float16)x.z; h[3] = (_Float16)x.w;
        *(half4v*)&kb[key][d] = h;
      }
    }
    // ---- stage V^T [dim][key], swizzled ----
    {
      const int kp2 = (t >> 3) * 2;      // even key
      const int m = t & 7;
      const int db = m * 8;
      const float* v0 = V + (size_t)(kt + kp2) * TOK + hoff + db;
      const float* v1 = v0 + TOK;
      float4 a0 = *(const float4*)v0;
      float4 a1 = *(const float4*)(v0 + 4);
      float4 b0 = *(const float4*)v1;
      float4 b1 = *(const float4*)(v1 + 4);
      float av[8] = {a0.x, a0.y, a0.z, a0.w, a1.x, a1.y, a1.z, a1.w};
      float bv[8] = {b0.x, b0.y, b0.z, b0.w, b1.x, b1.y, b1.z, b1.w};
      const int keyS = kp2 ^ (m << 3);   // (dim>>3)&7 == m for all 8 dims this thread writes
      #pragma unroll
      for (int j = 0; j < 8; ++j) {
        half2v h; h[0] = (_Float16)av[j]; h[1] = (_Float16)bv[j];
        *(half2v*)&vt[db + j][keyS] = h;
      }
    }
    __syncthreads();

    // ---- S^T = K . Q^T : frag mb covers keys 32mb..32mb+31 ----
    f32x16 sf0, sf1;
    {
      f32x16 c0, c1;
      #pragma unroll
      for (int r = 0; r < 16; ++r) { c0[r] = 0.f; c1[r] = 0.f; }
      #pragma unroll
      for (int ks = 0; ks < 4; ++ks) {
        half8v a0v = *(const half8v*)&kb[l31][8 * h2 + 16 * ks];
        half8v a1v = *(const half8v*)&kb[l31 + 32][8 * h2 + 16 * ks];
        c0 = __builtin_amdgcn_mfma_f32_32x32x16_f16(a0v, qf[ks], c0, 0, 0, 0);
        c1 = __builtin_amdgcn_mfma_f32_32x32x16_f16(a1v, qf[ks], c1, 0, 0, 0);
      }
      sf0 = c0; sf1 = c1;
    }

    // ---- online softmax (query = l31; partner lane = lane^32 holds other half of keys) ----
    float mx = -INFINITY;
    #pragma unroll
    for (int r = 0; r < 16; ++r) mx = fmaxf(mx, fmaxf(sf0[r], sf1[r]));
    mx = fmaxf(mx, __shfl_xor(mx, 32, 64));
    const float mnew = fmaxf(m_i, mx);
    const float alpha = __expf(m_i - mnew);   // 0 on first tile
    float rsum = 0.f;
    #pragma unroll
    for (int r = 0; r < 16; ++r) {
      float p0 = __expf(sf0[r] - mnew);
      float p1 = __expf(sf1[r] - mnew);
      sf0[r] = p0; sf1[r] = p1;
      rsum += p0 + p1;
    }
    rsum += __shfl_xor(rsum, 32, 64);
    l_i = l_i * alpha + rsum;
    m_i = mnew;
    #pragma unroll
    for (int r = 0; r < 16; ++r) { acc0[r] *= alpha; acc1[r] *= alpha; }

    // ---- PV: O^T += V^T . P^T with permuted k-order ----
    // kstep ks covers keys 16ks..16ks+15; element j <-> key 16ks + 4h2 + 8*(j>>2) + (j&3).
    // B operand (P^T) = C-layout regs rb+2t, rb+2t+1 packed; A operand = two b64 chunks of vt.
    #pragma unroll
    for (int ks = 0; ks < 4; ++ks) {
      const int rb = 8 * (ks & 1);
      const f32x16& s = (ks < 2) ? sf0 : sf1;   // keys 0-31 in sf0, 32-63 in sf1
      union { half8v v8; half2v v2[4]; } pu;
      #pragma unroll
      for (int tt = 0; tt < 4; ++tt) {
        auto pk = __builtin_amdgcn_cvt_pkrtz(s[rb + 2 * tt], s[rb + 2 * tt + 1]);
        pu.v2[tt] = *(half2v*)&pk;
      }
      #pragma unroll
      for (int mbd = 0; mbd < 2; ++mbd) {
        const int dim = l31 + 32 * mbd;
        const int swz = (dim >> 3) & 7;
        union { half8v v8; half4v v4[2]; } au;
        au.v4[0] = *(const half4v*)&vt[dim][(((2 * ks)     ^ swz) * 8) + 4 * h2];
        au.v4[1] = *(const half4v*)&vt[dim][(((2 * ks + 1) ^ swz) * 8) + 4 * h2];
        if (mbd == 0)
          acc0 = __builtin_amdgcn_mfma_f32_32x32x16_f16(au.v8, pu.v8, acc0, 0, 0, 0);
        else
          acc1 = __builtin_amdgcn_mfma_f32_32x32x16_f16(au.v8, pu.v8, acc1, 0, 0, 0);
      }
    }
  }

  // ---- epilogue: O^T C-layout -> global. row(dim) = (r&3)+8*(r>>2)+4*h2 (+32*mbd) ----
  const float invl = 1.f / l_i;
  float* orow = O + (size_t)(q0 + l31) * TOK + hoff;
  #pragma unroll
  for (int r = 0; r < 16; ++r) {
    const int d = (r & 3) + 8 * (r >> 2) + 4 * h2;
    orow[d]      = acc0[r] * invl;
    orow[d + 32] = acc1[r] * invl;
  }
}

extern "C" void kernel_launch(void* const* d_in, const int* in_sizes, int n_in,
                              void* d_out, int out_size, void* d_ws, size_t ws_size,
                              hipStream_t stream) {
  const float* Q = (const float*)d_in[0];
  const float* K = (const float*)d_in[1];
  const float* V = (const float*)d_in[2];
  float* O = (float*)d_out;
  dim3 grid(SQ / BQ, NBH);   // 16 x 32 = 512 blocks
  dim3 block(256);
  fattn_mfma<<<grid, block, 0, stream>>>(Q, K, V, O);
}